// Round 5
// baseline (3262.271 us; speedup 1.0000x reference)
//
#include <hip/hip_runtime.h>

#define NN 50000
#define NE 500000
#define DD 128
#define NL 4
#define NG 64
#define FIXED_DIM 10000
#define BN_EPS 1e-5f

typedef unsigned short u16;
typedef unsigned int u32;

__device__ __forceinline__ float bf2f(u16 u) {
    return __uint_as_float(((u32)u) << 16);
}
__device__ __forceinline__ u16 f2bf(float f) {
    u32 u = __float_as_uint(f);
    return (u16)((u + 0x7FFFu + ((u >> 16) & 1u)) >> 16);
}
// adaptive float-INPUT load (isbf: bf16 vs fp32) — belt-and-suspenders
__device__ __forceinline__ float ldf(const void* p, size_t i, int isbf) {
    return isbf ? bf2f(((const u16*)p)[i]) : ((const float*)p)[i];
}
// scratch B load/store, storage chosen at launch
template <bool B16>
__device__ __forceinline__ float lb(const void* p, size_t i) {
    return B16 ? bf2f(((const u16*)p)[i]) : ((const float*)p)[i];
}
template <bool B16>
__device__ __forceinline__ void sb(void* p, size_t i, float v) {
    if (B16) ((u16*)p)[i] = f2bf(v);
    else     ((float*)p)[i] = v;
}

// dtype probe on value_proj_b's first 128 u16 (256 B, in-bounds either way)
__global__ void k_detect(const void* __restrict__ vb, int* __restrict__ flag) {
    __shared__ int ok[128];
    int t = threadIdx.x;
    float v = bf2f(((const u16*)vb)[t]);
    ok[t] = (fabsf(v) < 1000.f) ? 1 : 0;   // NaN -> 0
    __syncthreads();
    for (int off = 64; off; off >>= 1) {
        if (t < off) ok[t] &= ok[t + off];
        __syncthreads();
    }
    if (t == 0) *flag = ok[0];             // 1 = bf16 inputs, 0 = fp32
}

__global__ void k_zero(float* __restrict__ p, int n) {
    int i = blockIdx.x * 256 + threadIdx.x;
    if (i < n) p[i] = 0.0f;
}
// convert float input -> fp32 scratch
__global__ void k_cvt(const void* __restrict__ src, float* __restrict__ dst,
                      int n, const int* __restrict__ flag) {
    int i = blockIdx.x * 256 + threadIdx.x;
    if (i < n) dst[i] = ldf(src, i, *flag);
}
__global__ void k_deg(const int* __restrict__ dst, int* __restrict__ deg) {
    int i = blockIdx.x * 256 + threadIdx.x;
    if (i < NE) atomicAdd(&deg[dst[i]], 1);
}
__global__ void k_gcnt(const int* __restrict__ batch, int* __restrict__ gcnt) {
    int i = blockIdx.x * 256 + threadIdx.x;
    if (i < NN) atomicAdd(&gcnt[batch[i]], 1);
}

// exclusive scan of deg -> rowptr[0..NN]
__global__ void k_scan(const int* __restrict__ deg, int* __restrict__ rowptr) {
    __shared__ int part[1024];
    const int t = threadIdx.x;
    const int chunk = (NN + 1023) / 1024;   // 49
    int lo = t * chunk;
    int hi = min(lo + chunk, NN);
    int s = 0;
    for (int i = lo; i < hi; i++) s += deg[i];
    part[t] = s;
    __syncthreads();
    for (int off = 1; off < 1024; off <<= 1) {
        int v = (t >= off) ? part[t - off] : 0;
        __syncthreads();
        part[t] += v;
        __syncthreads();
    }
    int run = (t == 0) ? 0 : part[t - 1];
    for (int i = lo; i < hi; i++) { rowptr[i] = run; run += deg[i]; }
    if (t == 1023) rowptr[NN] = run;        // == NE
}

__global__ void k_fill(const int* __restrict__ src, const int* __restrict__ dst,
                       const int* __restrict__ rowptr, int* __restrict__ cursor,
                       int* __restrict__ colidx) {
    int e = blockIdx.x * 256 + threadIdx.x;
    if (e >= NE) return;
    int d = dst[e];
    int p = atomicAdd(&cursor[d], 1);
    colidx[rowptr[d] + p] = src[e];
}

// h0 = vw[feat] + vb + deg_emb[min(deg,1000)] -> A (fp32, = d_out h region)
__global__ void k_init(const int* __restrict__ feat, const int* __restrict__ deg,
                       const void* __restrict__ vw, const void* __restrict__ vb,
                       const void* __restrict__ demb, float* __restrict__ A,
                       const int* __restrict__ flag) {
    int t = blockIdx.x * 256 + threadIdx.x;
    if (t >= NN * DD) return;
    int n = t >> 7, c = t & 127;
    int isbf = *flag;
    int f = feat[n] % FIXED_DIM;
    int dg = min(deg[n], 1000);
    A[t] = ldf(vw, (size_t)f * DD + c, isbf)
         + ldf(vb, c, isbf)
         + ldf(demb, (size_t)dg * DD + c, isbf);
}

// B[n] = A[n] + sum_{j in CSR row n} A[colidx[j]]
template <bool B16>
__global__ void k_aggr(const float* __restrict__ H, const int* __restrict__ rowptr,
                       const int* __restrict__ colidx, void* __restrict__ B) {
    int n = blockIdx.x;        // NN blocks
    int c = threadIdx.x;       // 128
    float s = H[(size_t)n * DD + c];
    int lo = rowptr[n], hi = rowptr[n + 1];
    for (int j = lo; j < hi; j++) {
        s += H[(size_t)colidx[j] * DD + c];
    }
    sb<B16>(B, (size_t)n * DD + c, s);
}

// Out[n,c] = sum_k f(In[n,k]) * W[k*DD+c] + bias[c]
// f(x) = useAff ? relu(aff[k]*x + aff[DD+k]) : x
template <bool IN16, bool OUT16>
__global__ void k_mm(const void* __restrict__ In, const float* __restrict__ W,
                     const float* __restrict__ bias,
                     const float* __restrict__ aff, int useAff,
                     void* __restrict__ Out) {
    int t = blockIdx.x * 256 + threadIdx.x;
    if (t >= NN * DD) return;
    int n = t >> 7, c = t & 127;
    float acc = 0.f;
    for (int k = 0; k < DD; k++) {
        float x = lb<IN16>(In, (size_t)n * DD + k);
        if (useAff) x = fmaxf(fmaf(aff[k], x, aff[DD + k]), 0.f);
        acc = fmaf(x, W[(size_t)k * DD + c], acc);
    }
    acc += bias[c];
    sb<OUT16>(Out, t, acc);
}

// per-column sum/sumsq over N rows (block = column)
template <bool Z16>
__global__ void k_stats(const void* __restrict__ Z, float* __restrict__ ssum,
                        float* __restrict__ ssq) {
    __shared__ float S[256], Q[256];
    int c = blockIdx.x, t = threadIdx.x;
    float s = 0.f, q = 0.f;
    for (int n = t; n < NN; n += 256) {
        float x = lb<Z16>(Z, (size_t)n * DD + c);
        s += x; q += x * x;
    }
    S[t] = s; Q[t] = q;
    __syncthreads();
    for (int off = 128; off; off >>= 1) {
        if (t < off) { S[t] += S[t + off]; Q[t] += Q[t + off]; }
        __syncthreads();
    }
    if (t == 0) { ssum[c] = S[0]; ssq[c] = Q[0]; }
}

// aff[c] = g*rsqrt(var+eps);  aff[DD+c] = beta - aff[c]*mu
__global__ void k_fin(const float* __restrict__ ssum, const float* __restrict__ ssq,
                      const void* __restrict__ g, const void* __restrict__ b,
                      size_t poff, float* __restrict__ aff,
                      const int* __restrict__ flag) {
    int c = threadIdx.x;
    int isbf = *flag;
    float inv = 1.0f / (float)NN;
    float mu = ssum[c] * inv;
    float var = fmaxf(ssq[c] * inv - mu * mu, 0.0f);
    float a = ldf(g, poff + c, isbf) * rsqrtf(var + BN_EPS);
    aff[c] = a;
    aff[DD + c] = ldf(b, poff + c, isbf) - a * mu;
}

// h = relu(aff*z2 + b) -> A (fp32 h output region); last layer: pool atomics
template <bool B16>
__global__ void k_update(const void* __restrict__ Bz, const float* __restrict__ aff,
                         float* __restrict__ A, float* __restrict__ gsum,
                         const int* __restrict__ batch, int last) {
    int t = blockIdx.x * 256 + threadIdx.x;
    if (t >= NN * DD) return;
    int n = t >> 7, c = t & 127;
    float v = fmaxf(fmaf(aff[c], lb<B16>(Bz, t), aff[DD + c]), 0.f);
    A[t] = v;
    if (last) atomicAdd(&gsum[(size_t)batch[n] * DD + c], v);
}

__global__ void k_pool(const float* __restrict__ gsum, const int* __restrict__ gcnt,
                       float* __restrict__ out) {
    int t = blockIdx.x * 256 + threadIdx.x;   // G*DD exact
    int g = t >> 7;
    float cnt = fmaxf((float)gcnt[g], 1.0f);
    out[t] = gsum[t] / cnt;
}

extern "C" void kernel_launch(void* const* d_in, const int* in_sizes, int n_in,
                              void* d_out, int out_size, void* d_ws, size_t ws_size,
                              hipStream_t stream) {
    const int* feat  = (const int*)d_in[0];
    const int* ei    = (const int*)d_in[1];
    const int* batch = (const int*)d_in[2];
    const void* vw   = d_in[3];
    const void* vb   = d_in[4];
    const void* demb = d_in[5];
    const void* w1   = d_in[6];
    const void* b1   = d_in[7];
    const void* g1   = d_in[8];
    const void* be1  = d_in[9];
    const void* w2   = d_in[10];
    const void* b2   = d_in[11];
    const void* g2   = d_in[12];
    const void* be2  = d_in[13];

    const int* src = ei;
    const int* dst = ei + NE;
    const size_t ND = (size_t)NN * DD;

    // ---- workspace layout ----
    float* stats  = (float*)d_ws;            // 256
    float* aff1   = stats + 256;             // 256
    float* aff2   = aff1 + 256;              // 256
    float* W1c    = aff2 + 256;              // NL*DD*DD = 65536
    float* W2c    = W1c + NL * DD * DD;      // 65536
    float* b1c    = W2c + NL * DD * DD;      // 512
    float* b2c    = b1c + NL * DD;           // 512
    int*   flag   = (int*)(b2c + NL * DD);   // 64
    float* gsum   = (float*)(flag + 64);     // 8192   [zero from here...]
    int*   deg    = (int*)(gsum + NG * DD);  // NN
    int*   gcnt   = deg + NN;                // NG
    int*   cursor = gcnt + NG;               // NN     [...to here]
    int*   rowptr = cursor + NN;             // NN+64
    int*   colidx = rowptr + NN + 64;        // NE
    void*  B      = (void*)(colidx + NE);    // ND fp32 or bf16

    size_t headBytes = (size_t)((char*)B - (char*)d_ws);
    const bool b16 = !(ws_size >= headBytes + ND * 4);   // fp32 B if it fits

    float* outw = (float*)d_out;             // [0, NG*DD): graph_feature
    float* A    = outw + (size_t)NG * DD;    // [NG*DD, +ND): h (doubles as buffer A)

    const int zwords = NG * DD + NN + NG + NN;   // gsum, deg, gcnt, cursor
    const int gridND = (int)((ND + 255) / 256);

    k_detect<<<1, 128, 0, stream>>>(vb, flag);
    k_zero<<<(zwords + 255) / 256, 256, 0, stream>>>(gsum, zwords);
    k_cvt<<<(NL * DD * DD + 255) / 256, 256, 0, stream>>>(w1, W1c, NL * DD * DD, flag);
    k_cvt<<<(NL * DD * DD + 255) / 256, 256, 0, stream>>>(w2, W2c, NL * DD * DD, flag);
    k_cvt<<<(NL * DD + 255) / 256, 256, 0, stream>>>(b1, b1c, NL * DD, flag);
    k_cvt<<<(NL * DD + 255) / 256, 256, 0, stream>>>(b2, b2c, NL * DD, flag);
    k_deg<<<(NE + 255) / 256, 256, 0, stream>>>(dst, deg);
    k_gcnt<<<(NN + 255) / 256, 256, 0, stream>>>(batch, gcnt);
    k_scan<<<1, 1024, 0, stream>>>(deg, rowptr);
    k_fill<<<(NE + 255) / 256, 256, 0, stream>>>(src, dst, rowptr, cursor, colidx);
    k_init<<<gridND, 256, 0, stream>>>(feat, deg, vw, vb, demb, A, flag);

    for (int l = 0; l < NL; l++) {
        const float* W1l = W1c + (size_t)l * DD * DD;
        const float* W2l = W2c + (size_t)l * DD * DD;
        const float* b1l = b1c + (size_t)l * DD;
        const float* b2l = b2c + (size_t)l * DD;
        const size_t boff = (size_t)l * DD;
        const int last = (l == NL - 1);

        if (b16) {
            k_aggr<true><<<NN, 128, 0, stream>>>(A, rowptr, colidx, B);
            k_mm<true, false><<<gridND, 256, 0, stream>>>(B, W1l, b1l, nullptr, 0, A);
            k_stats<false><<<DD, 256, 0, stream>>>(A, stats, stats + 128);
            k_fin<<<1, 128, 0, stream>>>(stats, stats + 128, g1, be1, boff, aff1, flag);
            k_mm<false, true><<<gridND, 256, 0, stream>>>(A, W2l, b2l, aff1, 1, B);
            k_stats<true><<<DD, 256, 0, stream>>>(B, stats, stats + 128);
            k_fin<<<1, 128, 0, stream>>>(stats, stats + 128, g2, be2, boff, aff2, flag);
            k_update<true><<<gridND, 256, 0, stream>>>(B, aff2, A, gsum, batch, last);
        } else {
            k_aggr<false><<<NN, 128, 0, stream>>>(A, rowptr, colidx, B);
            k_mm<false, false><<<gridND, 256, 0, stream>>>(B, W1l, b1l, nullptr, 0, A);
            k_stats<false><<<DD, 256, 0, stream>>>(A, stats, stats + 128);
            k_fin<<<1, 128, 0, stream>>>(stats, stats + 128, g1, be1, boff, aff1, flag);
            k_mm<false, false><<<gridND, 256, 0, stream>>>(A, W2l, b2l, aff1, 1, B);
            k_stats<false><<<DD, 256, 0, stream>>>(B, stats, stats + 128);
            k_fin<<<1, 128, 0, stream>>>(stats, stats + 128, g2, be2, boff, aff2, flag);
            k_update<false><<<gridND, 256, 0, stream>>>(B, aff2, A, gsum, batch, last);
        }
    }
    k_pool<<<(NG * DD + 255) / 256, 256, 0, stream>>>(gsum, gcnt, outw);
}

// Round 6
// 1607.123 us; speedup vs baseline: 2.0299x; 2.0299x over previous
//
#include <hip/hip_runtime.h>

#define NN 50000
#define NE 500000
#define DD 128
#define NL 4
#define NG 64
#define FIXED_DIM 10000
#define BN_EPS 1e-5f

typedef unsigned short u16;
typedef unsigned int u32;

__device__ __forceinline__ float bf2f(u16 u) {
    return __uint_as_float(((u32)u) << 16);
}
__device__ __forceinline__ u16 f2bf(float f) {
    u32 u = __float_as_uint(f);
    return (u16)((u + 0x7FFFu + ((u >> 16) & 1u)) >> 16);
}
// adaptive float-INPUT load (isbf: bf16 vs fp32) — belt-and-suspenders
__device__ __forceinline__ float ldf(const void* p, size_t i, int isbf) {
    return isbf ? bf2f(((const u16*)p)[i]) : ((const float*)p)[i];
}
// scratch B load/store, storage chosen at launch
template <bool B16>
__device__ __forceinline__ float lb(const void* p, size_t i) {
    return B16 ? bf2f(((const u16*)p)[i]) : ((const float*)p)[i];
}
template <bool B16>
__device__ __forceinline__ void sb(void* p, size_t i, float v) {
    if (B16) ((u16*)p)[i] = f2bf(v);
    else     ((float*)p)[i] = v;
}

// dtype probe on value_proj_b's first 128 u16 (256 B, in-bounds either way)
__global__ void k_detect(const void* __restrict__ vb, int* __restrict__ flag) {
    __shared__ int ok[128];
    int t = threadIdx.x;
    float v = bf2f(((const u16*)vb)[t]);
    ok[t] = (fabsf(v) < 1000.f) ? 1 : 0;   // NaN -> 0
    __syncthreads();
    for (int off = 64; off; off >>= 1) {
        if (t < off) ok[t] &= ok[t + off];
        __syncthreads();
    }
    if (t == 0) *flag = ok[0];             // 1 = bf16 inputs, 0 = fp32
}

__global__ void k_zero(float* __restrict__ p, int n) {
    int i = blockIdx.x * 256 + threadIdx.x;
    if (i < n) p[i] = 0.0f;
}
// convert float input -> fp32 scratch
__global__ void k_cvt(const void* __restrict__ src, float* __restrict__ dst,
                      int n, const int* __restrict__ flag) {
    int i = blockIdx.x * 256 + threadIdx.x;
    if (i < n) dst[i] = ldf(src, i, *flag);
}
__global__ void k_deg(const int* __restrict__ dst, int* __restrict__ deg) {
    int i = blockIdx.x * 256 + threadIdx.x;
    if (i < NE) atomicAdd(&deg[dst[i]], 1);
}
__global__ void k_gcnt(const int* __restrict__ batch, int* __restrict__ gcnt) {
    int i = blockIdx.x * 256 + threadIdx.x;
    if (i < NN) atomicAdd(&gcnt[batch[i]], 1);
}

// exclusive scan of deg -> rowptr[0..NN]
__global__ void k_scan(const int* __restrict__ deg, int* __restrict__ rowptr) {
    __shared__ int part[1024];
    const int t = threadIdx.x;
    const int chunk = (NN + 1023) / 1024;   // 49
    int lo = t * chunk;
    int hi = min(lo + chunk, NN);
    int s = 0;
    for (int i = lo; i < hi; i++) s += deg[i];
    part[t] = s;
    __syncthreads();
    for (int off = 1; off < 1024; off <<= 1) {
        int v = (t >= off) ? part[t - off] : 0;
        __syncthreads();
        part[t] += v;
        __syncthreads();
    }
    int run = (t == 0) ? 0 : part[t - 1];
    for (int i = lo; i < hi; i++) { rowptr[i] = run; run += deg[i]; }
    if (t == 1023) rowptr[NN] = run;        // == NE
}

__global__ void k_fill(const int* __restrict__ src, const int* __restrict__ dst,
                       const int* __restrict__ rowptr, int* __restrict__ cursor,
                       int* __restrict__ colidx) {
    int e = blockIdx.x * 256 + threadIdx.x;
    if (e >= NE) return;
    int d = dst[e];
    int p = atomicAdd(&cursor[d], 1);
    colidx[rowptr[d] + p] = src[e];
}

// h0 = vw[feat] + vb + deg_emb[min(deg,1000)] -> A (fp32, = d_out h region)
__global__ void k_init(const int* __restrict__ feat, const int* __restrict__ deg,
                       const void* __restrict__ vw, const void* __restrict__ vb,
                       const void* __restrict__ demb, float* __restrict__ A,
                       const int* __restrict__ flag) {
    int t = blockIdx.x * 256 + threadIdx.x;
    if (t >= NN * DD) return;
    int n = t >> 7, c = t & 127;
    int isbf = *flag;
    int f = feat[n] % FIXED_DIM;
    int dg = min(deg[n], 1000);
    A[t] = ldf(vw, (size_t)f * DD + c, isbf)
         + ldf(vb, c, isbf)
         + ldf(demb, (size_t)dg * DD + c, isbf);
}

// B[n] = A[n] + sum_{j in CSR row n} A[colidx[j]]
template <bool B16>
__global__ void k_aggr(const float* __restrict__ H, const int* __restrict__ rowptr,
                       const int* __restrict__ colidx, void* __restrict__ B) {
    int n = blockIdx.x;        // NN blocks
    int c = threadIdx.x;       // 128
    float s = H[(size_t)n * DD + c];
    int lo = rowptr[n], hi = rowptr[n + 1];
    for (int j = lo; j < hi; j++) {
        s += H[(size_t)colidx[j] * DD + c];
    }
    sb<B16>(B, (size_t)n * DD + c, s);
}

// ---- tiled GEMM: Out[r][c] = sum_k f(In[r][k]) * W[k][c] + bias[c] ----
// f(x) = AFF ? relu(aff[k]*x + aff[DD+k]) : x
// fused per-column sum/sumsq accumulated into ssum/ssq (pre-zeroed).
// block: 64 rows x 128 cols, 256 threads, 8x4 acc/thread, K-chunks of 32.
template <bool IN16, bool OUT16, bool AFF>
__global__ __launch_bounds__(256, 2) void k_gemm(
        const void* __restrict__ In, const float* __restrict__ W,
        const float* __restrict__ bias, const float* __restrict__ aff,
        void* __restrict__ Out, float* __restrict__ ssum, float* __restrict__ ssq,
        int nRows) {
    __shared__ float As[64 * 36];     // 64 rows x 32 k, pad to 36 (9.2 KB)
    __shared__ float Ws[32 * DD];     // 16 KB
    __shared__ float Red[256 * 8];    // 8 KB
    const int t = threadIdx.x;
    const int row0 = blockIdx.x * 64;
    const int c4 = (t & 31) * 4;
    const int rg = t >> 5;            // rows rg + 8*rr

    float acc[8][4];
    #pragma unroll
    for (int i = 0; i < 8; i++)
        #pragma unroll
        for (int j = 0; j < 4; j++) acc[i][j] = 0.f;

    for (int kc = 0; kc < DD; kc += 32) {
        __syncthreads();
        // stage W chunk: 32x128 = 1024 float4
        for (int i = t; i < 1024; i += 256) {
            *(float4*)&Ws[i * 4] = *(const float4*)&W[(size_t)kc * DD + i * 4];
        }
        // stage A chunk: 64 rows x 32 k = 512 float4
        for (int i = t; i < 512; i += 256) {
            int r  = i >> 3;
            int kk = (i & 7) * 4;
            int gr = row0 + r;
            float4 v = make_float4(0.f, 0.f, 0.f, 0.f);
            if (gr < nRows) {
                size_t base = (size_t)gr * DD + kc + kk;
                if (IN16) {
                    ushort4 u = *(const ushort4*)&((const u16*)In)[base];
                    v.x = bf2f(u.x); v.y = bf2f(u.y);
                    v.z = bf2f(u.z); v.w = bf2f(u.w);
                } else {
                    v = *(const float4*)&((const float*)In)[base];
                }
                if (AFF) {
                    int k = kc + kk;
                    v.x = fmaxf(fmaf(aff[k + 0], v.x, aff[DD + k + 0]), 0.f);
                    v.y = fmaxf(fmaf(aff[k + 1], v.y, aff[DD + k + 1]), 0.f);
                    v.z = fmaxf(fmaf(aff[k + 2], v.z, aff[DD + k + 2]), 0.f);
                    v.w = fmaxf(fmaf(aff[k + 3], v.w, aff[DD + k + 3]), 0.f);
                }
            }
            *(float4*)&As[r * 36 + kk] = v;
        }
        __syncthreads();
        // compute on the chunk
        for (int k4 = 0; k4 < 32; k4 += 4) {
            float wf[4][4];
            #pragma unroll
            for (int kk = 0; kk < 4; kk++) {
                float4 w = *(const float4*)&Ws[(k4 + kk) * DD + c4];
                wf[kk][0] = w.x; wf[kk][1] = w.y; wf[kk][2] = w.z; wf[kk][3] = w.w;
            }
            #pragma unroll
            for (int rr = 0; rr < 8; rr++) {
                float4 av = *(const float4*)&As[(rg + rr * 8) * 36 + k4];
                #pragma unroll
                for (int cc = 0; cc < 4; cc++) {
                    acc[rr][cc] = fmaf(av.x, wf[0][cc], acc[rr][cc]);
                    acc[rr][cc] = fmaf(av.y, wf[1][cc], acc[rr][cc]);
                    acc[rr][cc] = fmaf(av.z, wf[2][cc], acc[rr][cc]);
                    acc[rr][cc] = fmaf(av.w, wf[3][cc], acc[rr][cc]);
                }
            }
        }
    }

    // epilogue: +bias, store, fused column stats
    float4 bv = *(const float4*)&bias[c4];
    float lsum[4] = {0.f, 0.f, 0.f, 0.f};
    float lsq[4]  = {0.f, 0.f, 0.f, 0.f};
    #pragma unroll
    for (int rr = 0; rr < 8; rr++) {
        int gr = row0 + rg + rr * 8;
        if (gr < nRows) {
            float o0 = acc[rr][0] + bv.x;
            float o1 = acc[rr][1] + bv.y;
            float o2 = acc[rr][2] + bv.z;
            float o3 = acc[rr][3] + bv.w;
            size_t base = (size_t)gr * DD + c4;
            if (OUT16) {
                ushort4 u;
                u.x = f2bf(o0); u.y = f2bf(o1); u.z = f2bf(o2); u.w = f2bf(o3);
                *(ushort4*)&((u16*)Out)[base] = u;
            } else {
                *(float4*)&((float*)Out)[base] = make_float4(o0, o1, o2, o3);
            }
            lsum[0] += o0; lsq[0] += o0 * o0;
            lsum[1] += o1; lsq[1] += o1 * o1;
            lsum[2] += o2; lsq[2] += o2 * o2;
            lsum[3] += o3; lsq[3] += o3 * o3;
        }
    }
    float* my = &Red[t * 8];
    my[0] = lsum[0]; my[1] = lsum[1]; my[2] = lsum[2]; my[3] = lsum[3];
    my[4] = lsq[0];  my[5] = lsq[1];  my[6] = lsq[2];  my[7] = lsq[3];
    __syncthreads();
    if (t < 32) {
        float s[8];
        #pragma unroll
        for (int i = 0; i < 8; i++) s[i] = Red[t * 8 + i];
        for (int j = 1; j < 8; j++) {
            const float* o = &Red[(j * 32 + t) * 8];
            #pragma unroll
            for (int i = 0; i < 8; i++) s[i] += o[i];
        }
        #pragma unroll
        for (int i = 0; i < 4; i++) {
            atomicAdd(&ssum[t * 4 + i], s[i]);
            atomicAdd(&ssq[t * 4 + i], s[4 + i]);
        }
    }
}

// aff[c] = g*rsqrt(var+eps);  aff[DD+c] = beta - aff[c]*mu
__global__ void k_fin(const float* __restrict__ ssum, const float* __restrict__ ssq,
                      const void* __restrict__ g, const void* __restrict__ b,
                      size_t poff, float* __restrict__ aff,
                      const int* __restrict__ flag) {
    int c = threadIdx.x;
    int isbf = *flag;
    float inv = 1.0f / (float)NN;
    float mu = ssum[c] * inv;
    float var = fmaxf(ssq[c] * inv - mu * mu, 0.0f);
    float a = ldf(g, poff + c, isbf) * rsqrtf(var + BN_EPS);
    aff[c] = a;
    aff[DD + c] = ldf(b, poff + c, isbf) - a * mu;
}

// h = relu(aff*z2 + b) -> A (fp32 h output region); last layer: pool atomics
template <bool B16>
__global__ void k_update(const void* __restrict__ Bz, const float* __restrict__ aff,
                         float* __restrict__ A, float* __restrict__ gsum,
                         const int* __restrict__ batch, int last) {
    int t = blockIdx.x * 256 + threadIdx.x;
    if (t >= NN * DD) return;
    int n = t >> 7, c = t & 127;
    float v = fmaxf(fmaf(aff[c], lb<B16>(Bz, t), aff[DD + c]), 0.f);
    A[t] = v;
    if (last) atomicAdd(&gsum[(size_t)batch[n] * DD + c], v);
}

__global__ void k_pool(const float* __restrict__ gsum, const int* __restrict__ gcnt,
                       float* __restrict__ out) {
    int t = blockIdx.x * 256 + threadIdx.x;   // G*DD exact
    int g = t >> 7;
    float cnt = fmaxf((float)gcnt[g], 1.0f);
    out[t] = gsum[t] / cnt;
}

extern "C" void kernel_launch(void* const* d_in, const int* in_sizes, int n_in,
                              void* d_out, int out_size, void* d_ws, size_t ws_size,
                              hipStream_t stream) {
    const int* feat  = (const int*)d_in[0];
    const int* ei    = (const int*)d_in[1];
    const int* batch = (const int*)d_in[2];
    const void* vw   = d_in[3];
    const void* vb   = d_in[4];
    const void* demb = d_in[5];
    const void* w1   = d_in[6];
    const void* b1   = d_in[7];
    const void* g1   = d_in[8];
    const void* be1  = d_in[9];
    const void* w2   = d_in[10];
    const void* b2   = d_in[11];
    const void* g2   = d_in[12];
    const void* be2  = d_in[13];

    const int* src = ei;
    const int* dst = ei + NE;
    const size_t ND = (size_t)NN * DD;

    // ---- workspace layout ----
    float* stats  = (float*)d_ws;            // 512: [s1,q1,s2,q2]
    float* aff1   = stats + 512;             // 256
    float* aff2   = aff1 + 256;              // 256
    float* W1c    = aff2 + 256;              // NL*DD*DD = 65536
    float* W2c    = W1c + NL * DD * DD;      // 65536
    float* b1c    = W2c + NL * DD * DD;      // 512
    float* b2c    = b1c + NL * DD;           // 512
    int*   flag   = (int*)(b2c + NL * DD);   // 64
    float* gsum   = (float*)(flag + 64);     // 8192   [zero from here...]
    int*   deg    = (int*)(gsum + NG * DD);  // NN
    int*   gcnt   = deg + NN;                // NG
    int*   cursor = gcnt + NG;               // NN     [...to here]
    int*   rowptr = cursor + NN;             // NN+64
    int*   colidx = rowptr + NN + 64;        // NE
    void*  B      = (void*)(colidx + NE);    // ND fp32 or bf16

    size_t headBytes = (size_t)((char*)B - (char*)d_ws);
    const bool b16 = !(ws_size >= headBytes + ND * 4);   // fp32 B if it fits

    float* outw = (float*)d_out;             // [0, NG*DD): graph_feature
    float* A    = outw + (size_t)NG * DD;    // h region doubles as buffer A

    const int zwords = NG * DD + NN + NG + NN;   // gsum, deg, gcnt, cursor
    const int gridND = (int)((ND + 255) / 256);
    const int gemmBlocks = (NN + 63) / 64;       // 782

    k_detect<<<1, 128, 0, stream>>>(vb, flag);
    k_zero<<<(zwords + 255) / 256, 256, 0, stream>>>(gsum, zwords);
    k_cvt<<<(NL * DD * DD + 255) / 256, 256, 0, stream>>>(w1, W1c, NL * DD * DD, flag);
    k_cvt<<<(NL * DD * DD + 255) / 256, 256, 0, stream>>>(w2, W2c, NL * DD * DD, flag);
    k_cvt<<<(NL * DD + 255) / 256, 256, 0, stream>>>(b1, b1c, NL * DD, flag);
    k_cvt<<<(NL * DD + 255) / 256, 256, 0, stream>>>(b2, b2c, NL * DD, flag);
    k_deg<<<(NE + 255) / 256, 256, 0, stream>>>(dst, deg);
    k_gcnt<<<(NN + 255) / 256, 256, 0, stream>>>(batch, gcnt);
    k_scan<<<1, 1024, 0, stream>>>(deg, rowptr);
    k_fill<<<(NE + 255) / 256, 256, 0, stream>>>(src, dst, rowptr, cursor, colidx);
    k_init<<<gridND, 256, 0, stream>>>(feat, deg, vw, vb, demb, A, flag);

    for (int l = 0; l < NL; l++) {
        const float* W1l = W1c + (size_t)l * DD * DD;
        const float* W2l = W2c + (size_t)l * DD * DD;
        const float* b1l = b1c + (size_t)l * DD;
        const float* b2l = b2c + (size_t)l * DD;
        const size_t boff = (size_t)l * DD;
        const int last = (l == NL - 1);

        k_zero<<<2, 256, 0, stream>>>(stats, 512);
        if (b16) {
            k_aggr<true><<<NN, 128, 0, stream>>>(A, rowptr, colidx, B);
            k_gemm<true, false, false><<<gemmBlocks, 256, 0, stream>>>(
                B, W1l, b1l, nullptr, A, stats, stats + 128, NN);
            k_fin<<<1, 128, 0, stream>>>(stats, stats + 128, g1, be1, boff, aff1, flag);
            k_gemm<false, true, true><<<gemmBlocks, 256, 0, stream>>>(
                A, W2l, b2l, aff1, B, stats + 256, stats + 384, NN);
            k_fin<<<1, 128, 0, stream>>>(stats + 256, stats + 384, g2, be2, boff, aff2, flag);
            k_update<true><<<gridND, 256, 0, stream>>>(B, aff2, A, gsum, batch, last);
        } else {
            k_aggr<false><<<NN, 128, 0, stream>>>(A, rowptr, colidx, B);
            k_gemm<false, false, false><<<gemmBlocks, 256, 0, stream>>>(
                B, W1l, b1l, nullptr, A, stats, stats + 128, NN);
            k_fin<<<1, 128, 0, stream>>>(stats, stats + 128, g1, be1, boff, aff1, flag);
            k_gemm<false, false, true><<<gemmBlocks, 256, 0, stream>>>(
                A, W2l, b2l, aff1, B, stats + 256, stats + 384, NN);
            k_fin<<<1, 128, 0, stream>>>(stats + 256, stats + 384, g2, be2, boff, aff2, flag);
            k_update<false><<<gridND, 256, 0, stream>>>(B, aff2, A, gsum, batch, last);
        }
    }
    k_pool<<<(NG * DD + 255) / 256, 256, 0, stream>>>(gsum, gcnt, outw);
}

// Round 7
// 1436.034 us; speedup vs baseline: 2.2717x; 1.1191x over previous
//
#include <hip/hip_runtime.h>

#define NN 50000
#define NE 500000
#define DD 128
#define NL 4
#define NG 64
#define FIXED_DIM 10000
#define BN_EPS 1e-5f

typedef unsigned short u16;
typedef unsigned int u32;

__device__ __forceinline__ float bf2f(u16 u) {
    return __uint_as_float(((u32)u) << 16);
}
__device__ __forceinline__ u16 f2bf(float f) {
    u32 u = __float_as_uint(f);
    return (u16)((u + 0x7FFFu + ((u >> 16) & 1u)) >> 16);
}
// adaptive float-INPUT load (isbf: bf16 vs fp32) — belt-and-suspenders
__device__ __forceinline__ float ldf(const void* p, size_t i, int isbf) {
    return isbf ? bf2f(((const u16*)p)[i]) : ((const float*)p)[i];
}
// scratch B load/store, storage chosen at launch
template <bool B16>
__device__ __forceinline__ float lb(const void* p, size_t i) {
    return B16 ? bf2f(((const u16*)p)[i]) : ((const float*)p)[i];
}
template <bool B16>
__device__ __forceinline__ void sb(void* p, size_t i, float v) {
    if (B16) ((u16*)p)[i] = f2bf(v);
    else     ((float*)p)[i] = v;
}

// dtype probe on value_proj_b's first 128 u16 (256 B, in-bounds either way)
__global__ void k_detect(const void* __restrict__ vb, int* __restrict__ flag) {
    __shared__ int ok[128];
    int t = threadIdx.x;
    float v = bf2f(((const u16*)vb)[t]);
    ok[t] = (fabsf(v) < 1000.f) ? 1 : 0;   // NaN -> 0
    __syncthreads();
    for (int off = 64; off; off >>= 1) {
        if (t < off) ok[t] &= ok[t + off];
        __syncthreads();
    }
    if (t == 0) *flag = ok[0];             // 1 = bf16 inputs, 0 = fp32
}

__global__ void k_zero(float* __restrict__ p, int n) {
    int i = blockIdx.x * 256 + threadIdx.x;
    if (i < n) p[i] = 0.0f;
}
// convert float input -> fp32 scratch
__global__ void k_cvt(const void* __restrict__ src, float* __restrict__ dst,
                      int n, const int* __restrict__ flag) {
    int i = blockIdx.x * 256 + threadIdx.x;
    if (i < n) dst[i] = ldf(src, i, *flag);
}
__global__ void k_deg(const int* __restrict__ dst, int* __restrict__ deg) {
    int i = blockIdx.x * 256 + threadIdx.x;
    if (i < NE) atomicAdd(&deg[dst[i]], 1);
}
// batch is (near-)sorted: LDS histogram absorbs same-address contention,
// then 64 spread global atomics per block (196 blocks).
__global__ void k_gcnt(const int* __restrict__ batch, int* __restrict__ gcnt) {
    __shared__ int h[NG];
    int t = threadIdx.x;
    if (t < NG) h[t] = 0;
    __syncthreads();
    int i = blockIdx.x * 256 + t;
    if (i < NN) atomicAdd(&h[batch[i]], 1);
    __syncthreads();
    if (t < NG && h[t]) atomicAdd(&gcnt[t], h[t]);
}

// exclusive scan of deg -> rowptr[0..NN]
__global__ void k_scan(const int* __restrict__ deg, int* __restrict__ rowptr) {
    __shared__ int part[1024];
    const int t = threadIdx.x;
    const int chunk = (NN + 1023) / 1024;   // 49
    int lo = t * chunk;
    int hi = min(lo + chunk, NN);
    int s = 0;
    for (int i = lo; i < hi; i++) s += deg[i];
    part[t] = s;
    __syncthreads();
    for (int off = 1; off < 1024; off <<= 1) {
        int v = (t >= off) ? part[t - off] : 0;
        __syncthreads();
        part[t] += v;
        __syncthreads();
    }
    int run = (t == 0) ? 0 : part[t - 1];
    for (int i = lo; i < hi; i++) { rowptr[i] = run; run += deg[i]; }
    if (t == 1023) rowptr[NN] = run;        // == NE
}

__global__ void k_fill(const int* __restrict__ src, const int* __restrict__ dst,
                       const int* __restrict__ rowptr, int* __restrict__ cursor,
                       int* __restrict__ colidx) {
    int e = blockIdx.x * 256 + threadIdx.x;
    if (e >= NE) return;
    int d = dst[e];
    int p = atomicAdd(&cursor[d], 1);
    colidx[rowptr[d] + p] = src[e];
}

// h0 = vw[feat] + vb + deg_emb[min(deg,1000)] -> A (fp32, = d_out h region)
__global__ void k_init(const int* __restrict__ feat, const int* __restrict__ deg,
                       const void* __restrict__ vw, const void* __restrict__ vb,
                       const void* __restrict__ demb, float* __restrict__ A,
                       const int* __restrict__ flag) {
    int t = blockIdx.x * 256 + threadIdx.x;
    if (t >= NN * DD) return;
    int n = t >> 7, c = t & 127;
    int isbf = *flag;
    int f = feat[n] % FIXED_DIM;
    int dg = min(deg[n], 1000);
    A[t] = ldf(vw, (size_t)f * DD + c, isbf)
         + ldf(vb, c, isbf)
         + ldf(demb, (size_t)dg * DD + c, isbf);
}

// B[n] = A[n] + sum_{j in CSR row n} A[colidx[j]]
template <bool B16>
__global__ void k_aggr(const float* __restrict__ H, const int* __restrict__ rowptr,
                       const int* __restrict__ colidx, void* __restrict__ B) {
    int n = blockIdx.x;        // NN blocks
    int c = threadIdx.x;       // 128
    float s = H[(size_t)n * DD + c];
    int lo = rowptr[n], hi = rowptr[n + 1];
    for (int j = lo; j < hi; j++) {
        s += H[(size_t)colidx[j] * DD + c];
    }
    sb<B16>(B, (size_t)n * DD + c, s);
}

// ---- tiled GEMM: Out[r][c] = sum_k f(In[r][k]) * W[k][c] + bias[c] ----
// f(x) = AFF ? relu(aff[k]*x + aff[DD+k]) : x
// fused per-column sum/sumsq accumulated into ssum/ssq (pre-zeroed).
// block: 64 rows x 128 cols, 256 threads, 8x4 acc/thread, K-chunks of 32.
// launch_bounds(256,4): 4 waves/EU -> 4 blocks/CU (LDS 33.2 KB allows 4).
template <bool IN16, bool OUT16, bool AFF>
__global__ __launch_bounds__(256, 4) void k_gemm(
        const void* __restrict__ In, const float* __restrict__ W,
        const float* __restrict__ bias, const float* __restrict__ aff,
        void* __restrict__ Out, float* __restrict__ ssum, float* __restrict__ ssq,
        int nRows) {
    __shared__ float As[64 * 36];     // 64 rows x 32 k, pad to 36 (9.2 KB)
    __shared__ float Ws[32 * DD];     // 16 KB
    __shared__ float Red[256 * 8];    // 8 KB
    const int t = threadIdx.x;
    const int row0 = blockIdx.x * 64;
    const int c4 = (t & 31) * 4;
    const int rg = t >> 5;            // rows rg + 8*rr

    float acc[8][4];
    #pragma unroll
    for (int i = 0; i < 8; i++)
        #pragma unroll
        for (int j = 0; j < 4; j++) acc[i][j] = 0.f;

    for (int kc = 0; kc < DD; kc += 32) {
        __syncthreads();
        // stage W chunk: 32x128 = 1024 float4
        for (int i = t; i < 1024; i += 256) {
            *(float4*)&Ws[i * 4] = *(const float4*)&W[(size_t)kc * DD + i * 4];
        }
        // stage A chunk: 64 rows x 32 k = 512 float4
        for (int i = t; i < 512; i += 256) {
            int r  = i >> 3;
            int kk = (i & 7) * 4;
            int gr = row0 + r;
            float4 v = make_float4(0.f, 0.f, 0.f, 0.f);
            if (gr < nRows) {
                size_t base = (size_t)gr * DD + kc + kk;
                if (IN16) {
                    ushort4 u = *(const ushort4*)&((const u16*)In)[base];
                    v.x = bf2f(u.x); v.y = bf2f(u.y);
                    v.z = bf2f(u.z); v.w = bf2f(u.w);
                } else {
                    v = *(const float4*)&((const float*)In)[base];
                }
                if (AFF) {
                    int k = kc + kk;
                    v.x = fmaxf(fmaf(aff[k + 0], v.x, aff[DD + k + 0]), 0.f);
                    v.y = fmaxf(fmaf(aff[k + 1], v.y, aff[DD + k + 1]), 0.f);
                    v.z = fmaxf(fmaf(aff[k + 2], v.z, aff[DD + k + 2]), 0.f);
                    v.w = fmaxf(fmaf(aff[k + 3], v.w, aff[DD + k + 3]), 0.f);
                }
            }
            *(float4*)&As[r * 36 + kk] = v;
        }
        __syncthreads();
        // compute on the chunk
        for (int k4 = 0; k4 < 32; k4 += 4) {
            float wf[4][4];
            #pragma unroll
            for (int kk = 0; kk < 4; kk++) {
                float4 w = *(const float4*)&Ws[(k4 + kk) * DD + c4];
                wf[kk][0] = w.x; wf[kk][1] = w.y; wf[kk][2] = w.z; wf[kk][3] = w.w;
            }
            #pragma unroll
            for (int rr = 0; rr < 8; rr++) {
                float4 av = *(const float4*)&As[(rg + rr * 8) * 36 + k4];
                #pragma unroll
                for (int cc = 0; cc < 4; cc++) {
                    acc[rr][cc] = fmaf(av.x, wf[0][cc], acc[rr][cc]);
                    acc[rr][cc] = fmaf(av.y, wf[1][cc], acc[rr][cc]);
                    acc[rr][cc] = fmaf(av.z, wf[2][cc], acc[rr][cc]);
                    acc[rr][cc] = fmaf(av.w, wf[3][cc], acc[rr][cc]);
                }
            }
        }
    }

    // epilogue: +bias, store, fused column stats
    float4 bv = *(const float4*)&bias[c4];
    float lsum[4] = {0.f, 0.f, 0.f, 0.f};
    float lsq[4]  = {0.f, 0.f, 0.f, 0.f};
    #pragma unroll
    for (int rr = 0; rr < 8; rr++) {
        int gr = row0 + rg + rr * 8;
        if (gr < nRows) {
            float o0 = acc[rr][0] + bv.x;
            float o1 = acc[rr][1] + bv.y;
            float o2 = acc[rr][2] + bv.z;
            float o3 = acc[rr][3] + bv.w;
            size_t base = (size_t)gr * DD + c4;
            if (OUT16) {
                ushort4 u;
                u.x = f2bf(o0); u.y = f2bf(o1); u.z = f2bf(o2); u.w = f2bf(o3);
                *(ushort4*)&((u16*)Out)[base] = u;
            } else {
                *(float4*)&((float*)Out)[base] = make_float4(o0, o1, o2, o3);
            }
            lsum[0] += o0; lsq[0] += o0 * o0;
            lsum[1] += o1; lsq[1] += o1 * o1;
            lsum[2] += o2; lsq[2] += o2 * o2;
            lsum[3] += o3; lsq[3] += o3 * o3;
        }
    }
    float* my = &Red[t * 8];
    my[0] = lsum[0]; my[1] = lsum[1]; my[2] = lsum[2]; my[3] = lsum[3];
    my[4] = lsq[0];  my[5] = lsq[1];  my[6] = lsq[2];  my[7] = lsq[3];
    __syncthreads();
    if (t < 32) {
        float s[8];
        #pragma unroll
        for (int i = 0; i < 8; i++) s[i] = Red[t * 8 + i];
        for (int j = 1; j < 8; j++) {
            const float* o = &Red[(j * 32 + t) * 8];
            #pragma unroll
            for (int i = 0; i < 8; i++) s[i] += o[i];
        }
        #pragma unroll
        for (int i = 0; i < 4; i++) {
            atomicAdd(&ssum[t * 4 + i], s[i]);
            atomicAdd(&ssq[t * 4 + i], s[4 + i]);
        }
    }
}

// aff[c] = g*rsqrt(var+eps); aff[DD+c] = beta - aff[c]*mu.
// Re-zeros the consumed stats words so the initial zero is needed only once.
__global__ void k_fin(float* __restrict__ ssum, float* __restrict__ ssq,
                      const void* __restrict__ g, const void* __restrict__ b,
                      size_t poff, float* __restrict__ aff,
                      const int* __restrict__ flag) {
    int c = threadIdx.x;
    int isbf = *flag;
    float inv = 1.0f / (float)NN;
    float sv = ssum[c], qv = ssq[c];
    ssum[c] = 0.f; ssq[c] = 0.f;
    float mu = sv * inv;
    float var = fmaxf(qv * inv - mu * mu, 0.0f);
    float a = ldf(g, poff + c, isbf) * rsqrtf(var + BN_EPS);
    aff[c] = a;
    aff[DD + c] = ldf(b, poff + c, isbf) - a * mu;
}

// h = relu(aff*z2 + b) -> A (fp32 h output region); last layer: pool atomics
template <bool B16>
__global__ void k_update(const void* __restrict__ Bz, const float* __restrict__ aff,
                         float* __restrict__ A, float* __restrict__ gsum,
                         const int* __restrict__ batch, int last) {
    int t = blockIdx.x * 256 + threadIdx.x;
    if (t >= NN * DD) return;
    int n = t >> 7, c = t & 127;
    float v = fmaxf(fmaf(aff[c], lb<B16>(Bz, t), aff[DD + c]), 0.f);
    A[t] = v;
    if (last) atomicAdd(&gsum[(size_t)batch[n] * DD + c], v);
}

__global__ void k_pool(const float* __restrict__ gsum, const int* __restrict__ gcnt,
                       float* __restrict__ out) {
    int t = blockIdx.x * 256 + threadIdx.x;   // G*DD exact
    int g = t >> 7;
    float cnt = fmaxf((float)gcnt[g], 1.0f);
    out[t] = gsum[t] / cnt;
}

extern "C" void kernel_launch(void* const* d_in, const int* in_sizes, int n_in,
                              void* d_out, int out_size, void* d_ws, size_t ws_size,
                              hipStream_t stream) {
    const int* feat  = (const int*)d_in[0];
    const int* ei    = (const int*)d_in[1];
    const int* batch = (const int*)d_in[2];
    const void* vw   = d_in[3];
    const void* vb   = d_in[4];
    const void* demb = d_in[5];
    const void* w1   = d_in[6];
    const void* b1   = d_in[7];
    const void* g1   = d_in[8];
    const void* be1  = d_in[9];
    const void* w2   = d_in[10];
    const void* b2   = d_in[11];
    const void* g2   = d_in[12];
    const void* be2  = d_in[13];

    const int* src = ei;
    const int* dst = ei + NE;
    const size_t ND = (size_t)NN * DD;

    // ---- workspace layout ----
    float* stats  = (float*)d_ws;            // 512: [s1,q1,s2,q2]
    float* aff1   = stats + 512;             // 256
    float* aff2   = aff1 + 256;              // 256
    float* W1c    = aff2 + 256;              // NL*DD*DD = 65536
    float* W2c    = W1c + NL * DD * DD;      // 65536
    float* b1c    = W2c + NL * DD * DD;      // 512
    float* b2c    = b1c + NL * DD;           // 512
    int*   flag   = (int*)(b2c + NL * DD);   // 64
    float* gsum   = (float*)(flag + 64);     // 8192   [zero from here...]
    int*   deg    = (int*)(gsum + NG * DD);  // NN
    int*   gcnt   = deg + NN;                // NG
    int*   cursor = gcnt + NG;               // NN     [...to here]
    int*   rowptr = cursor + NN;             // NN+64
    int*   colidx = rowptr + NN + 64;        // NE
    void*  B      = (void*)(colidx + NE);    // ND fp32 or bf16

    size_t headBytes = (size_t)((char*)B - (char*)d_ws);
    const bool b16 = !(ws_size >= headBytes + ND * 4);   // fp32 B if it fits

    float* outw = (float*)d_out;             // [0, NG*DD): graph_feature
    float* A    = outw + (size_t)NG * DD;    // h region doubles as buffer A

    const int zwords = NG * DD + NN + NG + NN;   // gsum, deg, gcnt, cursor
    const int gridND = (int)((ND + 255) / 256);
    const int gemmBlocks = (NN + 63) / 64;       // 782

    k_detect<<<1, 128, 0, stream>>>(vb, flag);
    k_zero<<<(zwords + 255) / 256, 256, 0, stream>>>(gsum, zwords);
    k_zero<<<2, 256, 0, stream>>>(stats, 512);
    k_cvt<<<(NL * DD * DD + 255) / 256, 256, 0, stream>>>(w1, W1c, NL * DD * DD, flag);
    k_cvt<<<(NL * DD * DD + 255) / 256, 256, 0, stream>>>(w2, W2c, NL * DD * DD, flag);
    k_cvt<<<(NL * DD + 255) / 256, 256, 0, stream>>>(b1, b1c, NL * DD, flag);
    k_cvt<<<(NL * DD + 255) / 256, 256, 0, stream>>>(b2, b2c, NL * DD, flag);
    k_deg<<<(NE + 255) / 256, 256, 0, stream>>>(dst, deg);
    k_gcnt<<<(NN + 255) / 256, 256, 0, stream>>>(batch, gcnt);
    k_scan<<<1, 1024, 0, stream>>>(deg, rowptr);
    k_fill<<<(NE + 255) / 256, 256, 0, stream>>>(src, dst, rowptr, cursor, colidx);
    k_init<<<gridND, 256, 0, stream>>>(feat, deg, vw, vb, demb, A, flag);

    for (int l = 0; l < NL; l++) {
        const float* W1l = W1c + (size_t)l * DD * DD;
        const float* W2l = W2c + (size_t)l * DD * DD;
        const float* b1l = b1c + (size_t)l * DD;
        const float* b2l = b2c + (size_t)l * DD;
        const size_t boff = (size_t)l * DD;
        const int last = (l == NL - 1);

        if (b16) {
            k_aggr<true><<<NN, 128, 0, stream>>>(A, rowptr, colidx, B);
            k_gemm<true, false, false><<<gemmBlocks, 256, 0, stream>>>(
                B, W1l, b1l, nullptr, A, stats, stats + 128, NN);
            k_fin<<<1, 128, 0, stream>>>(stats, stats + 128, g1, be1, boff, aff1, flag);
            k_gemm<false, true, true><<<gemmBlocks, 256, 0, stream>>>(
                A, W2l, b2l, aff1, B, stats + 256, stats + 384, NN);
            k_fin<<<1, 128, 0, stream>>>(stats + 256, stats + 384, g2, be2, boff, aff2, flag);
            k_update<true><<<gridND, 256, 0, stream>>>(B, aff2, A, gsum, batch, last);
        } else {
            k_aggr<false><<<NN, 128, 0, stream>>>(A, rowptr, colidx, B);
            k_gemm<false, false, false><<<gemmBlocks, 256, 0, stream>>>(
                B, W1l, b1l, nullptr, A, stats, stats + 128, NN);
            k_fin<<<1, 128, 0, stream>>>(stats, stats + 128, g1, be1, boff, aff1, flag);
            k_gemm<false, false, true><<<gemmBlocks, 256, 0, stream>>>(
                A, W2l, b2l, aff1, B, stats + 256, stats + 384, NN);
            k_fin<<<1, 128, 0, stream>>>(stats + 256, stats + 384, g2, be2, boff, aff2, flag);
            k_update<false><<<gridND, 256, 0, stream>>>(B, aff2, A, gsum, batch, last);
        }
    }
    k_pool<<<(NG * DD + 255) / 256, 256, 0, stream>>>(gsum, gcnt, outw);
}

// Round 8
// 879.627 us; speedup vs baseline: 3.7087x; 1.6325x over previous
//
#include <hip/hip_runtime.h>

#define NN 50000
#define NE 500000
#define DD 128
#define NL 4
#define NG 64
#define FIXED_DIM 10000
#define BN_EPS 1e-5f

typedef unsigned short u16;
typedef unsigned int u32;
typedef __attribute__((ext_vector_type(8))) short bf16x8;
typedef __attribute__((ext_vector_type(4))) float f32x4;

__device__ __forceinline__ float bf2f(u16 u) {
    return __uint_as_float(((u32)u) << 16);
}
__device__ __forceinline__ u16 f2bf(float f) {
    u32 u = __float_as_uint(f);
    return (u16)((u + 0x7FFFu + ((u >> 16) & 1u)) >> 16);
}
// adaptive float-INPUT load (isbf: bf16 vs fp32)
__device__ __forceinline__ float ldf(const void* p, size_t i, int isbf) {
    return isbf ? bf2f(((const u16*)p)[i]) : ((const float*)p)[i];
}
template <bool B16>
__device__ __forceinline__ float lb(const void* p, size_t i) {
    return B16 ? bf2f(((const u16*)p)[i]) : ((const float*)p)[i];
}
template <bool B16>
__device__ __forceinline__ void sb(void* p, size_t i, float v) {
    if (B16) ((u16*)p)[i] = f2bf(v);
    else     ((float*)p)[i] = v;
}

// dtype probe on value_proj_b's first 128 u16 (256 B, in-bounds either way)
__global__ void k_detect(const void* __restrict__ vb, int* __restrict__ flag) {
    __shared__ int ok[128];
    int t = threadIdx.x;
    float v = bf2f(((const u16*)vb)[t]);
    ok[t] = (fabsf(v) < 1000.f) ? 1 : 0;   // NaN -> 0
    __syncthreads();
    for (int off = 64; off; off >>= 1) {
        if (t < off) ok[t] &= ok[t + off];
        __syncthreads();
    }
    if (t == 0) *flag = ok[0];             // 1 = bf16 inputs, 0 = fp32
}

__global__ void k_zero(float* __restrict__ p, int n) {
    int i = blockIdx.x * 256 + threadIdx.x;
    if (i < n) p[i] = 0.0f;
}
__global__ void k_cvt(const void* __restrict__ src, float* __restrict__ dst,
                      int n, const int* __restrict__ flag) {
    int i = blockIdx.x * 256 + threadIdx.x;
    if (i < n) dst[i] = ldf(src, i, *flag);
}
__global__ void k_deg(const int* __restrict__ dst, int* __restrict__ deg) {
    int i = blockIdx.x * 256 + threadIdx.x;
    if (i < NE) atomicAdd(&deg[dst[i]], 1);
}
// LDS histogram absorbs same-address contention of the sorted batch array
__global__ void k_gcnt(const int* __restrict__ batch, int* __restrict__ gcnt) {
    __shared__ int h[NG];
    int t = threadIdx.x;
    if (t < NG) h[t] = 0;
    __syncthreads();
    int i = blockIdx.x * 256 + t;
    if (i < NN) atomicAdd(&h[batch[i]], 1);
    __syncthreads();
    if (t < NG && h[t]) atomicAdd(&gcnt[t], h[t]);
}

// exclusive scan of deg -> rowptr[0..NN]
__global__ void k_scan(const int* __restrict__ deg, int* __restrict__ rowptr) {
    __shared__ int part[1024];
    const int t = threadIdx.x;
    const int chunk = (NN + 1023) / 1024;   // 49
    int lo = t * chunk;
    int hi = min(lo + chunk, NN);
    int s = 0;
    for (int i = lo; i < hi; i++) s += deg[i];
    part[t] = s;
    __syncthreads();
    for (int off = 1; off < 1024; off <<= 1) {
        int v = (t >= off) ? part[t - off] : 0;
        __syncthreads();
        part[t] += v;
        __syncthreads();
    }
    int run = (t == 0) ? 0 : part[t - 1];
    for (int i = lo; i < hi; i++) { rowptr[i] = run; run += deg[i]; }
    if (t == 1023) rowptr[NN] = run;        // == NE
}

__global__ void k_fill(const int* __restrict__ src, const int* __restrict__ dst,
                       const int* __restrict__ rowptr, int* __restrict__ cursor,
                       int* __restrict__ colidx) {
    int e = blockIdx.x * 256 + threadIdx.x;
    if (e >= NE) return;
    int d = dst[e];
    int p = atomicAdd(&cursor[d], 1);
    colidx[rowptr[d] + p] = src[e];
}

// pre-swizzle 8 weight matrices (W1 l=0..3 -> m=0..3, W2 -> m=4..7) into MFMA
// B-fragment order: Wsw[m*16384 + ((nt*4+ks)*64 + lane)*8 + j]
//   = W_m[ks*32 + (lane>>4)*8 + j][nt*16 + (lane&15)]   (bf16)
__global__ void k_swz(const void* __restrict__ w1, const void* __restrict__ w2,
                      u16* __restrict__ Wsw, const int* __restrict__ flag) {
    int t = blockIdx.x * 256 + threadIdx.x;   // 8*16384 = 131072
    if (t >= 8 * 16384) return;
    int m    = t >> 14;
    int idx  = t & 16383;
    int nt   = idx >> 11;
    int ks   = (idx >> 9) & 3;
    int lane = (idx >> 3) & 63;
    int j    = idx & 7;
    int row = ks * 32 + (lane >> 4) * 8 + j;
    int col = nt * 16 + (lane & 15);
    const void* src = (m < 4) ? w1 : w2;
    size_t off = (size_t)(m & 3) * DD * DD + (size_t)row * DD + col;
    Wsw[t] = f2bf(ldf(src, off, *flag));
}

// h0 = vw[feat] + vb + deg_emb[min(deg,1000)] -> A (fp32, = d_out h region)
__global__ void k_init(const int* __restrict__ feat, const int* __restrict__ deg,
                       const void* __restrict__ vw, const void* __restrict__ vb,
                       const void* __restrict__ demb, float* __restrict__ A,
                       const int* __restrict__ flag) {
    int t = blockIdx.x * 256 + threadIdx.x;
    if (t >= NN * DD) return;
    int n = t >> 7, c = t & 127;
    int isbf = *flag;
    int f = feat[n] % FIXED_DIM;
    int dg = min(deg[n], 1000);
    A[t] = ldf(vw, (size_t)f * DD + c, isbf)
         + ldf(vb, c, isbf)
         + ldf(demb, (size_t)dg * DD + c, isbf);
}

// B[n] = A[n] + sum_{j in CSR row n} A[colidx[j]]
template <bool B16>
__global__ void k_aggr(const float* __restrict__ H, const int* __restrict__ rowptr,
                       const int* __restrict__ colidx, void* __restrict__ B) {
    int n = blockIdx.x;        // NN blocks
    int c = threadIdx.x;       // 128
    float s = H[(size_t)n * DD + c];
    int lo = rowptr[n], hi = rowptr[n + 1];
    for (int j = lo; j < hi; j++) {
        s += H[(size_t)colidx[j] * DD + c];
    }
    sb<B16>(B, (size_t)n * DD + c, s);
}

// ---- MFMA GEMM: Out[r][c] = sum_k f(In[r][k]) * W[k][c] + bias[c] ----
// f(x) = AFF ? relu(aff[k]*x + aff[DD+k]) : x.  16x16x32 bf16 MFMA.
// Block: 64 rows x 128 cols, 4 waves; wave w owns rows w*16..w*16+15.
// Fused per-column sum/sumsq into ssum/ssq (pre-zeroed).
template <bool IN16, bool OUT16, bool AFF>
__global__ __launch_bounds__(256, 2) void k_gemm(
        const void* __restrict__ In, const u16* __restrict__ Wsw,
        const float* __restrict__ bias, const float* __restrict__ aff,
        void* __restrict__ Out, float* __restrict__ ssum, float* __restrict__ ssq,
        int nRows) {
    __shared__ u16 Wl[16384];          // 32 KB swizzled W
    __shared__ u16 At[64 * 136];       // 17.4 KB bf16 A-tile, pitch 136
    __shared__ float RedS[4 * 128];    // 2 KB
    __shared__ float RedQ[4 * 128];    // 2 KB
    const int t = threadIdx.x;
    const int row0 = blockIdx.x * 64;

    // stage swizzled W: 2048 uint4
    {
        const uint4* s = (const uint4*)Wsw;
        uint4* d = (uint4*)Wl;
        #pragma unroll
        for (int i = 0; i < 8; i++) d[t + i * 256] = s[t + i * 256];
    }
    // stage A-tile as bf16 (+optional affine+relu)
    for (int i = t; i < 2048; i += 256) {
        int r  = i >> 5;
        int c4 = (i & 31) * 4;
        int gr = row0 + r;
        float4 v = make_float4(0.f, 0.f, 0.f, 0.f);
        if (gr < nRows) {
            size_t base = (size_t)gr * DD + c4;
            if (IN16) {
                ushort4 u = *(const ushort4*)&((const u16*)In)[base];
                v.x = bf2f(u.x); v.y = bf2f(u.y); v.z = bf2f(u.z); v.w = bf2f(u.w);
            } else {
                v = *(const float4*)&((const float*)In)[base];
            }
            if (AFF) {
                v.x = fmaxf(fmaf(aff[c4 + 0], v.x, aff[DD + c4 + 0]), 0.f);
                v.y = fmaxf(fmaf(aff[c4 + 1], v.y, aff[DD + c4 + 1]), 0.f);
                v.z = fmaxf(fmaf(aff[c4 + 2], v.z, aff[DD + c4 + 2]), 0.f);
                v.w = fmaxf(fmaf(aff[c4 + 3], v.w, aff[DD + c4 + 3]), 0.f);
            }
        }
        ushort4 o;
        o.x = f2bf(v.x); o.y = f2bf(v.y); o.z = f2bf(v.z); o.w = f2bf(v.w);
        *(ushort4*)&At[r * 136 + c4] = o;
    }
    __syncthreads();

    const int w    = t >> 6;
    const int ln   = t & 63;
    const int quad = ln >> 4;
    const int lq   = ln & 15;

    f32x4 acc[8];
    #pragma unroll
    for (int nt = 0; nt < 8; nt++) acc[nt] = (f32x4){0.f, 0.f, 0.f, 0.f};

    // A frag: A[m=lq][k=ks*32+quad*8+j]; B frag: W[k=ks*32+quad*8+j][n=nt*16+lq]
    const u16* aRow = &At[(w * 16 + lq) * 136 + quad * 8];
    #pragma unroll
    for (int ks = 0; ks < 4; ks++) {
        bf16x8 a = *(const bf16x8*)&aRow[ks * 32];
        #pragma unroll
        for (int nt = 0; nt < 8; nt++) {
            bf16x8 b = *(const bf16x8*)&Wl[((nt * 4 + ks) * 64 + ln) * 8];
            acc[nt] = __builtin_amdgcn_mfma_f32_16x16x32_bf16(a, b, acc[nt], 0, 0, 0);
        }
    }

    // epilogue: D[row=quad*4+r][col=nt*16+lq]; +bias, store, fused stats
    const int rbase = row0 + w * 16 + quad * 4;
    #pragma unroll
    for (int nt = 0; nt < 8; nt++) {
        int col = nt * 16 + lq;
        float bv = bias[col];
        float s = 0.f, q = 0.f;
        #pragma unroll
        for (int r = 0; r < 4; r++) {
            int grow = rbase + r;
            if (grow < nRows) {
                float val = acc[nt][r] + bv;
                size_t o = (size_t)grow * DD + col;
                if (OUT16) ((u16*)Out)[o] = f2bf(val);
                else       ((float*)Out)[o] = val;
                s += val; q += val * val;
            }
        }
        s += __shfl_xor(s, 16); q += __shfl_xor(q, 16);
        s += __shfl_xor(s, 32); q += __shfl_xor(q, 32);
        if (quad == 0) { RedS[w * 128 + col] = s; RedQ[w * 128 + col] = q; }
    }
    __syncthreads();
    if (t < 128) {
        float s = RedS[t] + RedS[128 + t] + RedS[256 + t] + RedS[384 + t];
        float q = RedQ[t] + RedQ[128 + t] + RedQ[256 + t] + RedQ[384 + t];
        atomicAdd(&ssum[t], s);
        atomicAdd(&ssq[t], q);
    }
}

// aff[c] = g*rsqrt(var+eps); aff[DD+c] = beta - aff[c]*mu. Re-zeros stats.
__global__ void k_fin(float* __restrict__ ssum, float* __restrict__ ssq,
                      const void* __restrict__ g, const void* __restrict__ b,
                      size_t poff, float* __restrict__ aff,
                      const int* __restrict__ flag) {
    int c = threadIdx.x;
    int isbf = *flag;
    float inv = 1.0f / (float)NN;
    float sv = ssum[c], qv = ssq[c];
    ssum[c] = 0.f; ssq[c] = 0.f;
    float mu = sv * inv;
    float var = fmaxf(qv * inv - mu * mu, 0.0f);
    float a = ldf(g, poff + c, isbf) * rsqrtf(var + BN_EPS);
    aff[c] = a;
    aff[DD + c] = ldf(b, poff + c, isbf) - a * mu;
}

// h = relu(aff*z2 + b) -> A; last layer: pool atomics
template <bool B16>
__global__ void k_update(const void* __restrict__ Bz, const float* __restrict__ aff,
                         float* __restrict__ A, float* __restrict__ gsum,
                         const int* __restrict__ batch, int last) {
    int t = blockIdx.x * 256 + threadIdx.x;
    if (t >= NN * DD) return;
    int n = t >> 7, c = t & 127;
    float v = fmaxf(fmaf(aff[c], lb<B16>(Bz, t), aff[DD + c]), 0.f);
    A[t] = v;
    if (last) atomicAdd(&gsum[(size_t)batch[n] * DD + c], v);
}

__global__ void k_pool(const float* __restrict__ gsum, const int* __restrict__ gcnt,
                       float* __restrict__ out) {
    int t = blockIdx.x * 256 + threadIdx.x;   // G*DD exact
    int g = t >> 7;
    float cnt = fmaxf((float)gcnt[g], 1.0f);
    out[t] = gsum[t] / cnt;
}

extern "C" void kernel_launch(void* const* d_in, const int* in_sizes, int n_in,
                              void* d_out, int out_size, void* d_ws, size_t ws_size,
                              hipStream_t stream) {
    const int* feat  = (const int*)d_in[0];
    const int* ei    = (const int*)d_in[1];
    const int* batch = (const int*)d_in[2];
    const void* vw   = d_in[3];
    const void* vb   = d_in[4];
    const void* demb = d_in[5];
    const void* w1   = d_in[6];
    const void* b1   = d_in[7];
    const void* g1   = d_in[8];
    const void* be1  = d_in[9];
    const void* w2   = d_in[10];
    const void* b2   = d_in[11];
    const void* g2   = d_in[12];
    const void* be2  = d_in[13];

    const int* src = ei;
    const int* dst = ei + NE;
    const size_t ND = (size_t)NN * DD;

    // ---- workspace layout ----
    float* stats  = (float*)d_ws;            // 512: [s1,q1,s2,q2]
    float* aff1   = stats + 512;             // 256
    float* aff2   = aff1 + 256;              // 256
    float* b1c    = aff2 + 256;              // 512
    float* b2c    = b1c + NL * DD;           // 512
    int*   flag   = (int*)(b2c + NL * DD);   // 64
    u16*   Wsw    = (u16*)(flag + 64);       // 131072 u16 (8 swizzled 128x128)
    float* gsum   = (float*)(Wsw + 8 * 16384);   // 8192 [zero from here...]
    int*   deg    = (int*)(gsum + NG * DD);  // NN
    int*   gcnt   = deg + NN;                // NG
    int*   cursor = gcnt + NG;               // NN   [...to here]
    int*   rowptr = cursor + NN;             // NN+64
    int*   colidx = rowptr + NN + 64;        // NE
    void*  B      = (void*)(colidx + NE);    // ND fp32 or bf16

    size_t headBytes = (size_t)((char*)B - (char*)d_ws);
    const bool b16 = !(ws_size >= headBytes + ND * 4);   // fp32 B if it fits

    float* outw = (float*)d_out;             // [0, NG*DD): graph_feature
    float* A    = outw + (size_t)NG * DD;    // h region doubles as buffer A

    const int zwords = NG * DD + NN + NG + NN;   // gsum, deg, gcnt, cursor
    const int gridND = (int)((ND + 255) / 256);
    const int gemmBlocks = (NN + 63) / 64;       // 782

    k_detect<<<1, 128, 0, stream>>>(vb, flag);
    k_zero<<<(zwords + 255) / 256, 256, 0, stream>>>(gsum, zwords);
    k_zero<<<2, 256, 0, stream>>>(stats, 512);
    k_swz<<<(8 * 16384) / 256, 256, 0, stream>>>(w1, w2, Wsw, flag);
    k_cvt<<<(NL * DD + 255) / 256, 256, 0, stream>>>(b1, b1c, NL * DD, flag);
    k_cvt<<<(NL * DD + 255) / 256, 256, 0, stream>>>(b2, b2c, NL * DD, flag);
    k_deg<<<(NE + 255) / 256, 256, 0, stream>>>(dst, deg);
    k_gcnt<<<(NN + 255) / 256, 256, 0, stream>>>(batch, gcnt);
    k_scan<<<1, 1024, 0, stream>>>(deg, rowptr);
    k_fill<<<(NE + 255) / 256, 256, 0, stream>>>(src, dst, rowptr, cursor, colidx);
    k_init<<<gridND, 256, 0, stream>>>(feat, deg, vw, vb, demb, A, flag);

    for (int l = 0; l < NL; l++) {
        const u16* W1l = Wsw + (size_t)l * 16384;
        const u16* W2l = Wsw + (size_t)(4 + l) * 16384;
        const float* b1l = b1c + (size_t)l * DD;
        const float* b2l = b2c + (size_t)l * DD;
        const size_t boff = (size_t)l * DD;
        const int last = (l == NL - 1);

        if (b16) {
            k_aggr<true><<<NN, 128, 0, stream>>>(A, rowptr, colidx, B);
            k_gemm<true, false, false><<<gemmBlocks, 256, 0, stream>>>(
                B, W1l, b1l, nullptr, A, stats, stats + 128, NN);
            k_fin<<<1, 128, 0, stream>>>(stats, stats + 128, g1, be1, boff, aff1, flag);
            k_gemm<false, true, true><<<gemmBlocks, 256, 0, stream>>>(
                A, W2l, b2l, aff1, B, stats + 256, stats + 384, NN);
            k_fin<<<1, 128, 0, stream>>>(stats + 256, stats + 384, g2, be2, boff, aff2, flag);
            k_update<true><<<gridND, 256, 0, stream>>>(B, aff2, A, gsum, batch, last);
        } else {
            k_aggr<false><<<NN, 128, 0, stream>>>(A, rowptr, colidx, B);
            k_gemm<false, false, false><<<gemmBlocks, 256, 0, stream>>>(
                B, W1l, b1l, nullptr, A, stats, stats + 128, NN);
            k_fin<<<1, 128, 0, stream>>>(stats, stats + 128, g1, be1, boff, aff1, flag);
            k_gemm<false, false, true><<<gemmBlocks, 256, 0, stream>>>(
                A, W2l, b2l, aff1, B, stats + 256, stats + 384, NN);
            k_fin<<<1, 128, 0, stream>>>(stats + 256, stats + 384, g2, be2, boff, aff2, flag);
            k_update<false><<<gridND, 256, 0, stream>>>(B, aff2, A, gsum, batch, last);
        }
    }
    k_pool<<<(NG * DD + 255) / 256, 256, 0, stream>>>(gsum, gcnt, outw);
}

// Round 9
// 727.253 us; speedup vs baseline: 4.4857x; 1.2095x over previous
//
#include <hip/hip_runtime.h>

#define NN 50000
#define NE 500000
#define DD 128
#define NL 4
#define NG 64
#define FIXED_DIM 10000
#define BN_EPS 1e-5f
#define NB 196   // ceil(NN/256)

typedef unsigned short u16;
typedef unsigned int u32;
typedef __attribute__((ext_vector_type(8))) short bf16x8;
typedef __attribute__((ext_vector_type(4))) float f32x4;

__device__ __forceinline__ float bf2f(u16 u) {
    return __uint_as_float(((u32)u) << 16);
}
__device__ __forceinline__ u16 f2bf(float f) {
    u32 u = __float_as_uint(f);
    return (u16)((u + 0x7FFFu + ((u >> 16) & 1u)) >> 16);
}
// adaptive float-INPUT load (isbf: bf16 vs fp32)
__device__ __forceinline__ float ldf(const void* p, size_t i, int isbf) {
    return isbf ? bf2f(((const u16*)p)[i]) : ((const float*)p)[i];
}

// dtype probe on value_proj_b's first 128 u16 (256 B, in-bounds either way)
__global__ void k_detect(const void* __restrict__ vb, int* __restrict__ flag) {
    __shared__ int ok[128];
    int t = threadIdx.x;
    float v = bf2f(((const u16*)vb)[t]);
    ok[t] = (fabsf(v) < 1000.f) ? 1 : 0;   // NaN -> 0
    __syncthreads();
    for (int off = 64; off; off >>= 1) {
        if (t < off) ok[t] &= ok[t + off];
        __syncthreads();
    }
    if (t == 0) *flag = ok[0];             // 1 = bf16 inputs, 0 = fp32
}

__global__ void k_zero(float* __restrict__ p, int n) {
    int i = blockIdx.x * 256 + threadIdx.x;
    if (i < n) p[i] = 0.0f;
}
// convert 6 per-layer param tensors (each NL*DD) into one fp32 block:
// pc[0]=b1, [512]=b2, [1024]=g1, [1536]=be1, [2048]=g2, [2560]=be2
__global__ void k_cvt6(const void* b1, const void* b2, const void* g1,
                       const void* be1, const void* g2, const void* be2,
                       float* __restrict__ pc, const int* __restrict__ flag) {
    int t = blockIdx.x * 256 + threadIdx.x;
    if (t >= 6 * NL * DD) return;
    int p = t >> 9, j = t & 511;
    const void* s = (p == 0) ? b1 : (p == 1) ? b2 : (p == 2) ? g1
                  : (p == 3) ? be1 : (p == 4) ? g2 : be2;
    pc[t] = ldf(s, j, *flag);
}
__global__ void k_deg(const int* __restrict__ dst, int* __restrict__ deg) {
    int i = blockIdx.x * 256 + threadIdx.x;
    if (i < NE) atomicAdd(&deg[dst[i]], 1);
}
// LDS histogram absorbs same-address contention of the sorted batch array
__global__ void k_gcnt(const int* __restrict__ batch, int* __restrict__ gcnt) {
    __shared__ int h[NG];
    int t = threadIdx.x;
    if (t < NG) h[t] = 0;
    __syncthreads();
    int i = blockIdx.x * 256 + t;
    if (i < NN) atomicAdd(&h[batch[i]], 1);
    __syncthreads();
    if (t < NG && h[t]) atomicAdd(&gcnt[t], h[t]);
}

// ---- parallel exclusive scan of deg -> rowptr (3 stages) ----
__global__ void k_scan1(const int* __restrict__ deg, int* __restrict__ bsum) {
    __shared__ int S[256];
    int b = blockIdx.x, t = threadIdx.x;
    int i = b * 256 + t;
    S[t] = (i < NN) ? deg[i] : 0;
    __syncthreads();
    for (int off = 128; off; off >>= 1) {
        if (t < off) S[t] += S[t + off];
        __syncthreads();
    }
    if (t == 0) bsum[b] = S[0];
}
__global__ void k_scan2(int* __restrict__ bsum) {   // 1 block, 256 thr
    __shared__ int S[256];
    int t = threadIdx.x;
    int v = (t < NB) ? bsum[t] : 0;
    S[t] = v;
    __syncthreads();
    for (int off = 1; off < 256; off <<= 1) {
        int x = (t >= off) ? S[t - off] : 0;
        __syncthreads();
        S[t] += x;
        __syncthreads();
    }
    if (t < NB) bsum[t] = S[t] - v;                 // exclusive
}
__global__ void k_scan3(const int* __restrict__ deg, const int* __restrict__ bsum,
                        int* __restrict__ rowptr) {
    __shared__ int S[256];
    int b = blockIdx.x, t = threadIdx.x;
    int i = b * 256 + t;
    int v = (i < NN) ? deg[i] : 0;
    S[t] = v;
    __syncthreads();
    for (int off = 1; off < 256; off <<= 1) {
        int x = (t >= off) ? S[t - off] : 0;
        __syncthreads();
        S[t] += x;
        __syncthreads();
    }
    if (i < NN) rowptr[i] = bsum[b] + S[t] - v;
    if (i == NN - 1) rowptr[NN] = bsum[b] + S[t];   // == NE
}

__global__ void k_fill(const int* __restrict__ src, const int* __restrict__ dst,
                       const int* __restrict__ rowptr, int* __restrict__ cursor,
                       int* __restrict__ colidx) {
    int e = blockIdx.x * 256 + threadIdx.x;
    if (e >= NE) return;
    int d = dst[e];
    int p = atomicAdd(&cursor[d], 1);
    colidx[rowptr[d] + p] = src[e];
}

// pre-swizzle 8 weight matrices (W1 l=0..3 -> m=0..3, W2 -> m=4..7) into MFMA
// B-fragment order: Wsw[m*16384 + ((nt*4+ks)*64 + lane)*8 + j]
//   = W_m[ks*32 + (lane>>4)*8 + j][nt*16 + (lane&15)]   (bf16)
__global__ void k_swz(const void* __restrict__ w1, const void* __restrict__ w2,
                      u16* __restrict__ Wsw, const int* __restrict__ flag) {
    int t = blockIdx.x * 256 + threadIdx.x;   // 8*16384 = 131072
    if (t >= 8 * 16384) return;
    int m    = t >> 14;
    int idx  = t & 16383;
    int nt   = idx >> 11;
    int ks   = (idx >> 9) & 3;
    int lane = (idx >> 3) & 63;
    int j    = idx & 7;
    int row = ks * 32 + (lane >> 4) * 8 + j;
    int col = nt * 16 + (lane & 15);
    const void* src = (m < 4) ? w1 : w2;
    size_t off = (size_t)(m & 3) * DD * DD + (size_t)row * DD + col;
    Wsw[t] = f2bf(ldf(src, off, *flag));
}

// h0 = vw[feat] + vb + deg_emb[min(deg,1000)] -> B (bf16)
__global__ void k_init(const int* __restrict__ feat, const int* __restrict__ deg,
                       const void* __restrict__ vw, const void* __restrict__ vb,
                       const void* __restrict__ demb, u16* __restrict__ B,
                       const int* __restrict__ flag) {
    int t = blockIdx.x * 256 + threadIdx.x;
    if (t >= NN * DD) return;
    int n = t >> 7, c = t & 127;
    int isbf = *flag;
    int f = feat[n] % FIXED_DIM;
    int dg = min(deg[n], 1000);
    B[t] = f2bf(ldf(vw, (size_t)f * DD + c, isbf)
              + ldf(vb, c, isbf)
              + ldf(demb, (size_t)dg * DD + c, isbf));
}

// GIN aggregation with fused h-recompute:
//   f(x) = AFF ? relu(a[c]*x + b[c]) : x   (a,b from prev layer's BN2 stats)
//   A[n] = f(B[n]) + sum_{j in row n} f(B[colidx[j]])     (fp32 out)
// one wave per node; lane handles 2 columns via u32 load.
template <bool AFF>
__global__ __launch_bounds__(256, 4) void k_aggr(
        const u16* __restrict__ B, const int* __restrict__ rowptr,
        const int* __restrict__ colidx,
        const float* __restrict__ gIn, const float* __restrict__ bIn,
        const float* __restrict__ sIn, const float* __restrict__ qIn,
        float* __restrict__ A) {
    int n = blockIdx.x * 4 + (threadIdx.x >> 6);
    if (n >= NN) return;
    int c = (threadIdx.x & 63) * 2;
    float a0 = 1.f, b0 = 0.f, a1 = 1.f, b1 = 0.f;
    if (AFF) {
        float inv = 1.0f / (float)NN;
        float mu0 = sIn[c] * inv, mu1 = sIn[c + 1] * inv;
        float v0 = fmaxf(qIn[c] * inv - mu0 * mu0, 0.f);
        float v1 = fmaxf(qIn[c + 1] * inv - mu1 * mu1, 0.f);
        a0 = gIn[c] * rsqrtf(v0 + BN_EPS);
        a1 = gIn[c + 1] * rsqrtf(v1 + BN_EPS);
        b0 = bIn[c] - a0 * mu0;
        b1 = bIn[c + 1] - a1 * mu1;
    }
    u32 w = *(const u32*)&B[(size_t)n * DD + c];
    float x0 = bf2f((u16)(w & 0xFFFF)), x1 = bf2f((u16)(w >> 16));
    float s0 = AFF ? fmaxf(fmaf(a0, x0, b0), 0.f) : x0;
    float s1 = AFF ? fmaxf(fmaf(a1, x1, b1), 0.f) : x1;
    int lo = rowptr[n], hi = rowptr[n + 1];
    for (int j = lo; j < hi; j++) {
        int m = colidx[j];
        w = *(const u32*)&B[(size_t)m * DD + c];
        x0 = bf2f((u16)(w & 0xFFFF)); x1 = bf2f((u16)(w >> 16));
        s0 += AFF ? fmaxf(fmaf(a0, x0, b0), 0.f) : x0;
        s1 += AFF ? fmaxf(fmaf(a1, x1, b1), 0.f) : x1;
    }
    *(float2*)&A[(size_t)n * DD + c] = make_float2(s0, s1);
}

// ---- MFMA GEMM: Out[r][c] = sum_k f(In[r][k]) * W[k][c] + bias[c] ----
// f(x) = AFF ? relu(aff[k]*x + aff[DD+k]) : x, aff computed inline from stats.
// In fp32; Out fp32 (in-place A ok: rows are block-local) or bf16.
// Fused per-column sum/sumsq into per-layer ssum/ssq slots (zeroed once).
template <bool OUT16, bool AFF>
__global__ __launch_bounds__(256, 2) void k_gemm(
        const float* In, const u16* __restrict__ Wsw,
        const float* __restrict__ bias,
        const float* __restrict__ gIn, const float* __restrict__ bIn,
        const float* __restrict__ sIn, const float* __restrict__ qIn,
        void* Out, float* __restrict__ ssum, float* __restrict__ ssq,
        int nRows) {
    __shared__ u16 Wl[16384];          // 32 KB swizzled W
    __shared__ u16 At[64 * 136];       // 17.4 KB bf16 A-tile, pitch 136
    __shared__ float RedS[4 * 128];
    __shared__ float RedQ[4 * 128];
    __shared__ float affS[256];
    const int t = threadIdx.x;
    const int row0 = blockIdx.x * 64;

    if (AFF) {
        if (t < 128) {
            float inv = 1.0f / (float)NN;
            float mu = sIn[t] * inv;
            float var = fmaxf(qIn[t] * inv - mu * mu, 0.f);
            float a = gIn[t] * rsqrtf(var + BN_EPS);
            affS[t] = a;
            affS[128 + t] = bIn[t] - a * mu;
        }
        __syncthreads();
    }

    // stage swizzled W: 2048 uint4
    {
        const uint4* s = (const uint4*)Wsw;
        uint4* d = (uint4*)Wl;
        #pragma unroll
        for (int i = 0; i < 8; i++) d[t + i * 256] = s[t + i * 256];
    }
    // stage A-tile as bf16 (+optional affine+relu)
    for (int i = t; i < 2048; i += 256) {
        int r  = i >> 5;
        int c4 = (i & 31) * 4;
        int gr = row0 + r;
        float4 v = make_float4(0.f, 0.f, 0.f, 0.f);
        if (gr < nRows) {
            v = *(const float4*)&In[(size_t)gr * DD + c4];
            if (AFF) {
                v.x = fmaxf(fmaf(affS[c4 + 0], v.x, affS[128 + c4 + 0]), 0.f);
                v.y = fmaxf(fmaf(affS[c4 + 1], v.y, affS[128 + c4 + 1]), 0.f);
                v.z = fmaxf(fmaf(affS[c4 + 2], v.z, affS[128 + c4 + 2]), 0.f);
                v.w = fmaxf(fmaf(affS[c4 + 3], v.w, affS[128 + c4 + 3]), 0.f);
            }
        }
        ushort4 o;
        o.x = f2bf(v.x); o.y = f2bf(v.y); o.z = f2bf(v.z); o.w = f2bf(v.w);
        *(ushort4*)&At[r * 136 + c4] = o;
    }
    __syncthreads();

    const int w    = t >> 6;
    const int ln   = t & 63;
    const int quad = ln >> 4;
    const int lq   = ln & 15;

    f32x4 acc[8];
    #pragma unroll
    for (int nt = 0; nt < 8; nt++) acc[nt] = (f32x4){0.f, 0.f, 0.f, 0.f};

    const u16* aRow = &At[(w * 16 + lq) * 136 + quad * 8];
    #pragma unroll
    for (int ks = 0; ks < 4; ks++) {
        bf16x8 a = *(const bf16x8*)&aRow[ks * 32];
        #pragma unroll
        for (int nt = 0; nt < 8; nt++) {
            bf16x8 b = *(const bf16x8*)&Wl[((nt * 4 + ks) * 64 + ln) * 8];
            acc[nt] = __builtin_amdgcn_mfma_f32_16x16x32_bf16(a, b, acc[nt], 0, 0, 0);
        }
    }

    // epilogue: D[row=quad*4+r][col=nt*16+lq]; +bias, store, fused stats
    const int rbase = row0 + w * 16 + quad * 4;
    #pragma unroll
    for (int nt = 0; nt < 8; nt++) {
        int col = nt * 16 + lq;
        float bv = bias[col];
        float s = 0.f, q = 0.f;
        #pragma unroll
        for (int r = 0; r < 4; r++) {
            int grow = rbase + r;
            if (grow < nRows) {
                float val = acc[nt][r] + bv;
                size_t o = (size_t)grow * DD + col;
                if (OUT16) ((u16*)Out)[o] = f2bf(val);
                else       ((float*)Out)[o] = val;
                s += val; q += val * val;
            }
        }
        s += __shfl_xor(s, 16); q += __shfl_xor(q, 16);
        s += __shfl_xor(s, 32); q += __shfl_xor(q, 32);
        if (quad == 0) { RedS[w * 128 + col] = s; RedQ[w * 128 + col] = q; }
    }
    __syncthreads();
    if (t < 128) {
        float s = RedS[t] + RedS[128 + t] + RedS[256 + t] + RedS[384 + t];
        float q = RedQ[t] + RedQ[128 + t] + RedQ[256 + t] + RedQ[384 + t];
        atomicAdd(&ssum[t], s);
        atomicAdd(&ssq[t], q);
    }
}

// final h = relu(a*z2 + b) -> A (fp32 h output) + pool atomics (last layer only)
__global__ void k_update(const u16* __restrict__ Bz,
                         const float* __restrict__ gIn, const float* __restrict__ bIn,
                         const float* __restrict__ sIn, const float* __restrict__ qIn,
                         float* __restrict__ A, float* __restrict__ gsum,
                         const int* __restrict__ batch) {
    int t = blockIdx.x * 256 + threadIdx.x;
    if (t >= NN * DD) return;
    int n = t >> 7, c = t & 127;
    float inv = 1.0f / (float)NN;
    float mu = sIn[c] * inv;
    float var = fmaxf(qIn[c] * inv - mu * mu, 0.f);
    float a = gIn[c] * rsqrtf(var + BN_EPS);
    float bb = bIn[c] - a * mu;
    float v = fmaxf(fmaf(a, bf2f(Bz[t]), bb), 0.f);
    A[t] = v;
    atomicAdd(&gsum[(size_t)batch[n] * DD + c], v);
}

__global__ void k_pool(const float* __restrict__ gsum, const int* __restrict__ gcnt,
                       float* __restrict__ out) {
    int t = blockIdx.x * 256 + threadIdx.x;   // G*DD exact
    int g = t >> 7;
    float cnt = fmaxf((float)gcnt[g], 1.0f);
    out[t] = gsum[t] / cnt;
}

extern "C" void kernel_launch(void* const* d_in, const int* in_sizes, int n_in,
                              void* d_out, int out_size, void* d_ws, size_t ws_size,
                              hipStream_t stream) {
    const int* feat  = (const int*)d_in[0];
    const int* ei    = (const int*)d_in[1];
    const int* batch = (const int*)d_in[2];
    const void* vw   = d_in[3];
    const void* vb   = d_in[4];
    const void* demb = d_in[5];
    const void* w1   = d_in[6];
    const void* b1   = d_in[7];
    const void* g1   = d_in[8];
    const void* be1  = d_in[9];
    const void* w2   = d_in[10];
    const void* b2   = d_in[11];
    const void* g2   = d_in[12];
    const void* be2  = d_in[13];

    const int* src = ei;
    const int* dst = ei + NE;
    const size_t ND = (size_t)NN * DD;

    // ---- workspace layout (~15.7 MB total; R5/R8 prove ws >= this) ----
    float* pc     = (float*)d_ws;            // 3072: b1,b2,g1,be1,g2,be2
    int*   flag   = (int*)(pc + 3072);       // 64
    float* stats  = (float*)(flag + 64);     // 2048 [zero from here...]
    float* gsum   = stats + 2048;            // 8192
    int*   deg    = (int*)(gsum + NG * DD);  // NN
    int*   gcnt   = deg + NN;                // NG
    int*   cursor = gcnt + NG;               // NN   [...to here]
    int*   bsum   = cursor + NN;             // 256
    int*   rowptr = bsum + 256;              // NN+64
    int*   colidx = rowptr + NN + 64;        // NE
    u16*   Wsw    = (u16*)(colidx + NE);     // 8*16384 u16
    u16*   B      = Wsw + 8 * 16384;         // ND bf16

    float* b1c  = pc;
    float* b2c  = pc + 512;
    float* g1c  = pc + 1024;
    float* be1c = pc + 1536;
    float* g2c  = pc + 2048;
    float* be2c = pc + 2560;
    float* sum1 = stats;          // [NL][128]
    float* sq1  = stats + 512;
    float* sum2 = stats + 1024;
    float* sq2  = stats + 1536;

    float* outw = (float*)d_out;             // [0, NG*DD): graph_feature
    float* A    = outw + (size_t)NG * DD;    // h region doubles as fp32 buffer A

    const int zwords = 2048 + NG * DD + NN + NG + NN;   // stats..cursor
    const int gridND = (int)((ND + 255) / 256);
    const int gemmBlocks = (NN + 63) / 64;              // 782
    const int aggrBlocks = (NN + 3) / 4;                // 12500

    k_detect<<<1, 128, 0, stream>>>(vb, flag);
    k_zero<<<(zwords + 255) / 256, 256, 0, stream>>>(stats, zwords);
    k_cvt6<<<(6 * NL * DD + 255) / 256, 256, 0, stream>>>(b1, b2, g1, be1, g2, be2, pc, flag);
    k_swz<<<(8 * 16384) / 256, 256, 0, stream>>>(w1, w2, Wsw, flag);
    k_deg<<<(NE + 255) / 256, 256, 0, stream>>>(dst, deg);
    k_gcnt<<<NB, 256, 0, stream>>>(batch, gcnt);
    k_scan1<<<NB, 256, 0, stream>>>(deg, bsum);
    k_scan2<<<1, 256, 0, stream>>>(bsum);
    k_scan3<<<NB, 256, 0, stream>>>(deg, bsum, rowptr);
    k_fill<<<(NE + 255) / 256, 256, 0, stream>>>(src, dst, rowptr, cursor, colidx);
    k_init<<<gridND, 256, 0, stream>>>(feat, deg, vw, vb, demb, B, flag);

    for (int l = 0; l < NL; l++) {
        const u16* W1l = Wsw + (size_t)l * 16384;
        const u16* W2l = Wsw + (size_t)(4 + l) * 16384;
        if (l == 0) {
            k_aggr<false><<<aggrBlocks, 256, 0, stream>>>(
                B, rowptr, colidx, nullptr, nullptr, nullptr, nullptr, A);
        } else {
            k_aggr<true><<<aggrBlocks, 256, 0, stream>>>(
                B, rowptr, colidx, g2c + (l - 1) * 128, be2c + (l - 1) * 128,
                sum2 + (l - 1) * 128, sq2 + (l - 1) * 128, A);
        }
        k_gemm<false, false><<<gemmBlocks, 256, 0, stream>>>(
            A, W1l, b1c + l * 128, nullptr, nullptr, nullptr, nullptr,
            A, sum1 + l * 128, sq1 + l * 128, NN);
        k_gemm<true, true><<<gemmBlocks, 256, 0, stream>>>(
            A, W2l, b2c + l * 128, g1c + l * 128, be1c + l * 128,
            sum1 + l * 128, sq1 + l * 128,
            B, sum2 + l * 128, sq2 + l * 128, NN);
    }
    k_update<<<gridND, 256, 0, stream>>>(
        B, g2c + 3 * 128, be2c + 3 * 128, sum2 + 3 * 128, sq2 + 3 * 128,
        A, gsum, batch);
    k_pool<<<(NG * DD + 255) / 256, 256, 0, stream>>>(gsum, gcnt, outw);
}